// Round 4
// baseline (467.543 us; speedup 1.0000x reference)
//
#include <hip/hip_runtime.h>
#include <hip/hip_bf16.h>
#include <math.h>

#define T_TOK 8192
#define C_DIM 512
#define I_DIM 2048
#define E_NUM 16

#define BT 128
#define ISPLIT 8
#define IRANGE (I_DIM / ISPLIT) /* 256 */
#define BI 32
#define NCHUNK (IRANGE / BI) /* 8 */
#define CAP 640
#define BT2 32

// ws layout (bytes); peak use ~84 MB (< proven 111 MB)
#define WS_COUNTS 0
#define WS_THR 64
#define WS_INVS 128
#define WS_RW 192
#define WS_LISTS 524480
#define WS_XB 1048768
#define WS_POS 9437376
#define WS_MASKB 9961664
#define WS_WT 10485760ull                      /* shared by W1T then W2T, 33.5 MB */
#define WS_H 44040192ull                       /* bf16 H [E][CAP][I], 40 MB */

// out offsets (float elements)
#define OUT_FULL 4194304ull
#define OUT_LOGITS 71303168ull
#define OUT_MASK 71434240ull

typedef __attribute__((ext_vector_type(8))) short bf16x8;
typedef __attribute__((ext_vector_type(4))) float f32x4;

__device__ inline unsigned short f2bf(float f) {
  unsigned u = __float_as_uint(f);
  unsigned r = u + 0x7fffu + ((u >> 16) & 1u);
  return (unsigned short)(r >> 16);
}

__device__ inline bf16x8 ldb8(const unsigned short* p) {
  union { uint4 u; bf16x8 v; } w;
  w.u = *(const uint4*)p;
  return w.v;
}

__device__ inline float gelu_f(float x) {
  return 0.5f * x * (1.0f + erff(x * 0.7071067811865476f));
}

__global__ void prep_kernel(const float* __restrict__ sim, const float* __restrict__ gates,
                            char* __restrict__ wsb) {
  int e = threadIdx.x;
  if (e < E_NUM) {
    ((float*)(wsb + WS_THR))[e] = 1.0f / (1.0f + expf(-gates[e]));
    float ss = 0.0f;
    for (int c = 0; c < C_DIM; ++c) {
      float v = sim[c * E_NUM + e];
      ss += v * v;
    }
    float n = fmaxf(sqrtf(ss), 1e-12f);
    ((float*)(wsb + WS_INVS))[e] = 1.0f / n;
  }
}

// Per-token routing. No atomics: per-token results + 16-bit mask word only.
__global__ void router_kernel(const float* __restrict__ x, const float* __restrict__ sim,
                              char* __restrict__ wsb, float* __restrict__ out) {
  const int lane = threadIdx.x & 63;
  const int t = blockIdx.x * 4 + (threadIdx.x >> 6);

  const float4* xr = (const float4*)(x + (size_t)t * C_DIM + lane * 8);
  float4 v0 = xr[0], v1 = xr[1];
  float xv[8] = {v0.x, v0.y, v0.z, v0.w, v1.x, v1.y, v1.z, v1.w};

  unsigned p[4];
#pragma unroll
  for (int j = 0; j < 4; ++j)
    p[j] = (unsigned)f2bf(xv[2 * j]) | ((unsigned)f2bf(xv[2 * j + 1]) << 16);
  uint4 pk = {p[0], p[1], p[2], p[3]};
  *(uint4*)((unsigned short*)(wsb + WS_XB) + (size_t)t * C_DIM + lane * 8) = pk;

  float ss = 0.0f;
  float acc[E_NUM];
#pragma unroll
  for (int e = 0; e < E_NUM; ++e) acc[e] = 0.0f;

#pragma unroll
  for (int j = 0; j < 8; ++j) {
    const int c = lane * 8 + j;
    const float xd = xv[j];
    ss += xd * xd;
    const float4* sr = (const float4*)(sim + c * E_NUM);
    float4 s0 = sr[0], s1 = sr[1], s2 = sr[2], s3 = sr[3];
    acc[0] += xd * s0.x;   acc[1] += xd * s0.y;
    acc[2] += xd * s0.z;   acc[3] += xd * s0.w;
    acc[4] += xd * s1.x;   acc[5] += xd * s1.y;
    acc[6] += xd * s1.z;   acc[7] += xd * s1.w;
    acc[8] += xd * s2.x;   acc[9] += xd * s2.y;
    acc[10] += xd * s2.z;  acc[11] += xd * s2.w;
    acc[12] += xd * s3.x;  acc[13] += xd * s3.y;
    acc[14] += xd * s3.z;  acc[15] += xd * s3.w;
  }

#define BRED(v)                 \
  v += __shfl_xor(v, 32);       \
  v += __shfl_xor(v, 16);       \
  v += __shfl_xor(v, 8);        \
  v += __shfl_xor(v, 4);        \
  v += __shfl_xor(v, 2);        \
  v += __shfl_xor(v, 1);

  BRED(ss)
#pragma unroll
  for (int e = 0; e < E_NUM; ++e) { BRED(acc[e]) }

  const float invx = 1.0f / fmaxf(sqrtf(ss), 1e-12f);
  const float* thr = (const float*)(wsb + WS_THR);
  const float* invs = (const float*)(wsb + WS_INVS);

  float lg[E_NUM], gt[E_NUM];
  bool mk[E_NUM];
  bool any = false;
#pragma unroll
  for (int e = 0; e < E_NUM; ++e) {
    lg[e] = acc[e] * invx * invs[e];
    float d = lg[e] - thr[e];
    gt[e] = d > 0.0f ? d : 0.0f;
    mk[e] = d > 0.0f;
    any = any || mk[e];
  }
  if (!any) {  // fallback: one-hot argmax (first max, like np.argmax)
    int be = 0;
    float bv = lg[0];
#pragma unroll
    for (int e = 1; e < E_NUM; ++e) {
      if (lg[e] > bv) { bv = lg[e]; be = e; }
    }
#pragma unroll
    for (int e = 0; e < E_NUM; ++e) mk[e] = (e == be);
  }
  float mx = -1e30f;
#pragma unroll
  for (int e = 0; e < E_NUM; ++e) {
    float v = mk[e] ? gt[e] : -1e9f;
    if (v > mx) mx = v;
  }
  float sum = 0.0f;
  float ex[E_NUM];
#pragma unroll
  for (int e = 0; e < E_NUM; ++e) {
    ex[e] = mk[e] ? expf(gt[e] - mx) : 0.0f;
    sum += ex[e];
  }
  const float isum = 1.0f / sum;

  if (lane == 0) {
    float* lg_out = out + OUT_LOGITS + (size_t)t * E_NUM;
    float* mk_out = out + OUT_MASK + (size_t)t * E_NUM;
    float* rw = (float*)(wsb + WS_RW) + (size_t)t * E_NUM;
    unsigned mb = 0;
#pragma unroll
    for (int e = 0; e < E_NUM; ++e) {
      lg_out[e] = lg[e];
      mk_out[e] = mk[e] ? 1.0f : 0.0f;
      rw[e] = ex[e] * isum;
      if (mk[e]) mb |= (1u << e);
    }
    ((unsigned*)(wsb + WS_MASKB))[t] = mb;
  }
}

// Deterministic list build: one block per expert, prefix-scan over 8192 mask bits.
__global__ __launch_bounds__(1024) void build_lists_kernel(char* __restrict__ wsb) {
  const int e = blockIdx.x;
  const int tid = threadIdx.x;
  const unsigned* maskb = (const unsigned*)(wsb + WS_MASKB);
  const int t0 = tid * 8;
  unsigned flags = 0;
#pragma unroll
  for (int j = 0; j < 8; ++j)
    if (maskb[t0 + j] & (1u << e)) flags |= (1u << j);
  const int cnt = __popc(flags);
  const int lane = tid & 63, wid = tid >> 6;
  int v = cnt;
#pragma unroll
  for (int off = 1; off < 64; off <<= 1) {
    int u = __shfl_up(v, off);
    if (lane >= off) v += u;
  }
  __shared__ int wsum[16];
  if (lane == 63) wsum[wid] = v;
  __syncthreads();
  if (tid == 0) {
    int run = 0;
#pragma unroll
    for (int i = 0; i < 16; ++i) {
      int c = wsum[i];
      wsum[i] = run;
      run += c;
    }
    ((int*)(wsb + WS_COUNTS))[e] = run;
  }
  __syncthreads();
  int pos = wsum[wid] + v - cnt;  // exclusive prefix for this thread
  int* lists = (int*)(wsb + WS_LISTS) + e * T_TOK;
  int* posm = (int*)(wsb + WS_POS);
#pragma unroll
  for (int j = 0; j < 8; ++j) {
    const int t = t0 + j;
    int p = -1;
    if (flags & (1u << j)) {
      p = pos++;
      lists[p] = t;
    }
    posm[t * E_NUM + e] = p;
  }
}

// Tiled transpose+convert: src f32 [E][R][Cin] -> dst bf16 [E][Cin][R]
__global__ void transpose_kernel(const float* __restrict__ src, unsigned short* __restrict__ dst,
                                 int R, int Cin) {
  const int e = blockIdx.z;
  const int rt = blockIdx.y * 64, ct = blockIdx.x * 64;
  const float* se = src + (size_t)e * R * Cin;
  unsigned short* de = dst + (size_t)e * R * Cin;
  __shared__ unsigned short tile[64][68];
  const int tid = threadIdx.x;
  const int tr = tid >> 4, tc = (tid & 15) * 4;
#pragma unroll
  for (int it = 0; it < 4; ++it) {
    const int r = tr + it * 16;
    const float4 v = *(const float4*)(se + (size_t)(rt + r) * Cin + ct + tc);
    tile[tc + 0][r] = f2bf(v.x);
    tile[tc + 1][r] = f2bf(v.y);
    tile[tc + 2][r] = f2bf(v.z);
    tile[tc + 3][r] = f2bf(v.w);
  }
  __syncthreads();
#pragma unroll
  for (int it = 0; it < 4; ++it) {
    const int c = tr + it * 16;
    ushort4 o = *(const ushort4*)&tile[c][tc];
    *(ushort4*)(de + (size_t)(ct + c) * R + rt + tc) = o;
  }
}

// Stage 1: H[e][pos][i] = gelu(X @ W1), bf16, plain stores (block owns its rows x I-slice).
__global__ __launch_bounds__(512) void h_kernel(const char* __restrict__ wsb,
                                                unsigned short* __restrict__ hbuf) {
  const int e = blockIdx.x;
  const int ne = min(((const int*)(wsb + WS_COUNTS))[e], CAP);
  const int m0 = blockIdx.y * BT;
  if (m0 >= ne) return;
  const int i0 = blockIdx.z * IRANGE;

  const int* lists = (const int*)(wsb + WS_LISTS);
  const unsigned short* xb = (const unsigned short*)(wsb + WS_XB);
  const unsigned short* w1t = (const unsigned short*)(wsb + WS_WT) + (size_t)e * I_DIM * C_DIM;

  __shared__ int tl[BT];
  __shared__ unsigned short s_h[BT][40];

  const int tid = threadIdx.x;
  if (tid < BT) tl[tid] = lists[e * T_TOK + min(m0 + tid, ne - 1)];
  __syncthreads();

  const int wv = tid >> 6, lane = tid & 63, g = lane >> 4, l15 = lane & 15;
  const int nt1 = wv & 1, mg = wv >> 1;
  const f32x4 zero4 = {0.f, 0.f, 0.f, 0.f};

  const unsigned short* a0p = xb + (size_t)tl[mg * 32 + l15] * C_DIM;
  const unsigned short* a1p = xb + (size_t)tl[mg * 32 + 16 + l15] * C_DIM;
  unsigned short* hb = hbuf + (size_t)(e * CAP + m0 + (tid >> 2)) * I_DIM + i0 + (tid & 3) * 8;

  for (int ci = 0; ci < NCHUNK; ++ci) {
    f32x4 h0 = zero4, h1 = zero4;
    const unsigned short* brow = w1t + (size_t)(i0 + ci * BI + nt1 * 16 + l15) * C_DIM;
#pragma unroll
    for (int kk = 0; kk < 16; ++kk) {
      const int k0 = kk * 32 + g * 8;
      const bf16x8 b = ldb8(brow + k0);
      h0 = __builtin_amdgcn_mfma_f32_16x16x32_bf16(ldb8(a0p + k0), b, h0, 0, 0, 0);
      h1 = __builtin_amdgcn_mfma_f32_16x16x32_bf16(ldb8(a1p + k0), b, h1, 0, 0, 0);
    }
    __syncthreads();  // previous chunk's s_h reads complete
    {
      const int col = nt1 * 16 + l15;
      const int rb = mg * 32 + g * 4;
#pragma unroll
      for (int r = 0; r < 4; ++r) {
        s_h[rb + r][col] = f2bf(gelu_f(h0[r]));
        s_h[rb + 16 + r][col] = f2bf(gelu_f(h1[r]));
      }
    }
    __syncthreads();
    *(uint4*)(hb + ci * BI) = *(const uint4*)(&s_h[tid >> 2][(tid & 3) * 8]);
  }
}

// Stage 2: full[t][e][:] = H[e][pos][:] @ W2T (k = full I, no cross-block accumulation).
__global__ __launch_bounds__(512) void o_kernel(const char* __restrict__ wsb,
                                                const unsigned short* __restrict__ hbuf,
                                                float* __restrict__ out) {
  const int e = blockIdx.x;
  const int ne = min(((const int*)(wsb + WS_COUNTS))[e], CAP);
  const int m0 = blockIdx.y * BT2;
  if (m0 >= ne) return;
  const int mcnt = min(BT2, ne - m0);
  const int c0 = blockIdx.z * 256;

  const int* lists = (const int*)(wsb + WS_LISTS);
  const unsigned short* w2t = (const unsigned short*)(wsb + WS_WT) + (size_t)e * C_DIM * I_DIM;

  __shared__ int tl[BT2];
  const int tid = threadIdx.x;
  if (tid < BT2) tl[tid] = lists[e * T_TOK + min(m0 + tid, ne - 1)];
  __syncthreads();

  const int wv = tid >> 6, lane = tid & 63, g = lane >> 4, l15 = lane & 15;
  const f32x4 zero4 = {0.f, 0.f, 0.f, 0.f};
  f32x4 acc00 = zero4, acc01 = zero4, acc10 = zero4, acc11 = zero4;

  const unsigned short* h0p = hbuf + (size_t)(e * CAP + m0 + l15) * I_DIM;
  const unsigned short* h1p = h0p + 16 * I_DIM;
  const unsigned short* b0p = w2t + (size_t)(c0 + wv * 32 + l15) * I_DIM;
  const unsigned short* b1p = b0p + 16 * I_DIM;

#pragma unroll 4
  for (int kc = 0; kc < I_DIM / 32; ++kc) {
    const int k0 = kc * 32 + g * 8;
    const bf16x8 a0 = ldb8(h0p + k0), a1 = ldb8(h1p + k0);
    const bf16x8 b0 = ldb8(b0p + k0), b1 = ldb8(b1p + k0);
    acc00 = __builtin_amdgcn_mfma_f32_16x16x32_bf16(a0, b0, acc00, 0, 0, 0);
    acc01 = __builtin_amdgcn_mfma_f32_16x16x32_bf16(a0, b1, acc01, 0, 0, 0);
    acc10 = __builtin_amdgcn_mfma_f32_16x16x32_bf16(a1, b0, acc10, 0, 0, 0);
    acc11 = __builtin_amdgcn_mfma_f32_16x16x32_bf16(a1, b1, acc11, 0, 0, 0);
  }

#pragma unroll
  for (int r = 0; r < 4; ++r) {
    const int row0 = g * 4 + r, row1 = 16 + g * 4 + r;
    if (row0 < mcnt) {
      float* dst = out + OUT_FULL + ((size_t)tl[row0] * E_NUM + e) * C_DIM + c0 + wv * 32 + l15;
      dst[0] = acc00[r];
      dst[16] = acc01[r];
    }
    if (row1 < mcnt) {
      float* dst = out + OUT_FULL + ((size_t)tl[row1] * E_NUM + e) * C_DIM + c0 + wv * 32 + l15;
      dst[0] = acc10[r];
      dst[16] = acc11[r];
    }
  }
}

// Zero-fill inactive rows of full + final = sum_e rw * full (active rows already written).
__global__ void scatter_kernel(const char* __restrict__ wsb, float* __restrict__ out) {
  const int t = blockIdx.x;
  const int tid = threadIdx.x;  // 256
  __shared__ float rws[E_NUM];
  __shared__ int ps[E_NUM];
  if (tid < E_NUM) {
    rws[tid] = ((const float*)(wsb + WS_RW))[t * E_NUM + tid];
    ps[tid] = ((const int*)(wsb + WS_POS))[t * E_NUM + tid];
  }
  __syncthreads();
  float a0 = 0.f, a1 = 0.f;
  float* full = out + OUT_FULL + (size_t)t * E_NUM * C_DIM;
#pragma unroll 1
  for (int e = 0; e < E_NUM; ++e) {
    const int p = ps[e];
    if (p >= 0 && p < CAP) {
      const float w = rws[e];
      a0 += w * full[e * C_DIM + tid];
      a1 += w * full[e * C_DIM + tid + 256];
    } else {
      full[e * C_DIM + tid] = 0.f;
      full[e * C_DIM + tid + 256] = 0.f;
    }
  }
  out[(size_t)t * C_DIM + tid] = a0;
  out[(size_t)t * C_DIM + tid + 256] = a1;
}

extern "C" void kernel_launch(void* const* d_in, const int* in_sizes, int n_in,
                              void* d_out, int out_size, void* d_ws, size_t ws_size,
                              hipStream_t stream) {
  const float* x = (const float*)d_in[0];
  const float* sim = (const float*)d_in[1];
  const float* gates = (const float*)d_in[2];
  const float* w1 = (const float*)d_in[3];
  const float* w2 = (const float*)d_in[4];
  float* out = (float*)d_out;
  char* wsb = (char*)d_ws;
  unsigned short* wt = (unsigned short*)(wsb + WS_WT);
  unsigned short* hbuf = (unsigned short*)(wsb + WS_H);

  hipLaunchKernelGGL(prep_kernel, dim3(1), dim3(64), 0, stream, sim, gates, wsb);
  hipLaunchKernelGGL(router_kernel, dim3(T_TOK / 4), dim3(256), 0, stream, x, sim, wsb, out);
  hipLaunchKernelGGL(build_lists_kernel, dim3(E_NUM), dim3(1024), 0, stream, wsb);

  // W1 [E][512][2048] -> WT = W1T [E][2048][512]
  hipLaunchKernelGGL(transpose_kernel, dim3(I_DIM / 64, C_DIM / 64, E_NUM), dim3(256), 0, stream,
                     w1, wt, C_DIM, I_DIM);
  hipLaunchKernelGGL(h_kernel, dim3(E_NUM, CAP / BT, ISPLIT), dim3(512), 0, stream, wsb, hbuf);
  // W2 [E][2048][512] -> WT = W2T [E][512][2048]  (reuses the same region)
  hipLaunchKernelGGL(transpose_kernel, dim3(C_DIM / 64, I_DIM / 64, E_NUM), dim3(256), 0, stream,
                     w2, wt, I_DIM, C_DIM);
  hipLaunchKernelGGL(o_kernel, dim3(E_NUM, CAP / BT2, 2), dim3(512), 0, stream, wsb, hbuf, out);
  hipLaunchKernelGGL(scatter_kernel, dim3(T_TOK), dim3(256), 0, stream, wsb, out);
}

// Round 5
// 243.252 us; speedup vs baseline: 1.9220x; 1.9220x over previous
//
#include <hip/hip_runtime.h>
#include <hip/hip_bf16.h>
#include <math.h>

#define T_TOK 8192
#define C_DIM 512
#define I_DIM 2048
#define E_NUM 16
#define CAP 640

// ws layout (bytes); peak use ~86 MB (< proven 111 MB)
#define WS_COUNTS 0
#define WS_THR 64
#define WS_INVS 128
#define WS_RW 192
#define WS_LISTS 524480
#define WS_XB 1048768
#define WS_POS 9437376
#define WS_MASKB 9961664
#define WS_WT 10485760ull /* shared by W1T then W2T, 33.5 MB */
#define WS_H 44040192ull  /* bf16 H [E][CAP][I], 41.9 MB */

// out offsets (float elements)
#define OUT_FULL 4194304ull
#define OUT_LOGITS 71303168ull
#define OUT_MASK 71434240ull

typedef __attribute__((ext_vector_type(8))) short bf16x8;
typedef __attribute__((ext_vector_type(4))) float f32x4;

__device__ inline unsigned short f2bf(float f) {
  unsigned u = __float_as_uint(f);
  unsigned r = u + 0x7fffu + ((u >> 16) & 1u);
  return (unsigned short)(r >> 16);
}

__device__ inline bf16x8 ldb8(const unsigned short* p) {
  union { uint4 u; bf16x8 v; } w;
  w.u = *(const uint4*)p;
  return w.v;
}

__device__ inline float gelu_f(float x) {
  return 0.5f * x * (1.0f + erff(x * 0.7071067811865476f));
}

__global__ void prep_kernel(const float* __restrict__ sim, const float* __restrict__ gates,
                            char* __restrict__ wsb) {
  int e = threadIdx.x;
  if (e < E_NUM) {
    ((float*)(wsb + WS_THR))[e] = 1.0f / (1.0f + expf(-gates[e]));
    float ss = 0.0f;
    for (int c = 0; c < C_DIM; ++c) {
      float v = sim[c * E_NUM + e];
      ss += v * v;
    }
    float n = fmaxf(sqrtf(ss), 1e-12f);
    ((float*)(wsb + WS_INVS))[e] = 1.0f / n;
  }
}

// Per-token routing. No atomics: per-token results + 16-bit mask word only.
__global__ void router_kernel(const float* __restrict__ x, const float* __restrict__ sim,
                              char* __restrict__ wsb, float* __restrict__ out) {
  const int lane = threadIdx.x & 63;
  const int t = blockIdx.x * 4 + (threadIdx.x >> 6);

  const float4* xr = (const float4*)(x + (size_t)t * C_DIM + lane * 8);
  float4 v0 = xr[0], v1 = xr[1];
  float xv[8] = {v0.x, v0.y, v0.z, v0.w, v1.x, v1.y, v1.z, v1.w};

  unsigned p[4];
#pragma unroll
  for (int j = 0; j < 4; ++j)
    p[j] = (unsigned)f2bf(xv[2 * j]) | ((unsigned)f2bf(xv[2 * j + 1]) << 16);
  uint4 pk = {p[0], p[1], p[2], p[3]};
  *(uint4*)((unsigned short*)(wsb + WS_XB) + (size_t)t * C_DIM + lane * 8) = pk;

  float ss = 0.0f;
  float acc[E_NUM];
#pragma unroll
  for (int e = 0; e < E_NUM; ++e) acc[e] = 0.0f;

#pragma unroll
  for (int j = 0; j < 8; ++j) {
    const int c = lane * 8 + j;
    const float xd = xv[j];
    ss += xd * xd;
    const float4* sr = (const float4*)(sim + c * E_NUM);
    float4 s0 = sr[0], s1 = sr[1], s2 = sr[2], s3 = sr[3];
    acc[0] += xd * s0.x;   acc[1] += xd * s0.y;
    acc[2] += xd * s0.z;   acc[3] += xd * s0.w;
    acc[4] += xd * s1.x;   acc[5] += xd * s1.y;
    acc[6] += xd * s1.z;   acc[7] += xd * s1.w;
    acc[8] += xd * s2.x;   acc[9] += xd * s2.y;
    acc[10] += xd * s2.z;  acc[11] += xd * s2.w;
    acc[12] += xd * s3.x;  acc[13] += xd * s3.y;
    acc[14] += xd * s3.z;  acc[15] += xd * s3.w;
  }

#define BRED(v)                 \
  v += __shfl_xor(v, 32);       \
  v += __shfl_xor(v, 16);       \
  v += __shfl_xor(v, 8);        \
  v += __shfl_xor(v, 4);        \
  v += __shfl_xor(v, 2);        \
  v += __shfl_xor(v, 1);

  BRED(ss)
#pragma unroll
  for (int e = 0; e < E_NUM; ++e) { BRED(acc[e]) }

  const float invx = 1.0f / fmaxf(sqrtf(ss), 1e-12f);
  const float* thr = (const float*)(wsb + WS_THR);
  const float* invs = (const float*)(wsb + WS_INVS);

  float lg[E_NUM], gt[E_NUM];
  bool mk[E_NUM];
  bool any = false;
#pragma unroll
  for (int e = 0; e < E_NUM; ++e) {
    lg[e] = acc[e] * invx * invs[e];
    float d = lg[e] - thr[e];
    gt[e] = d > 0.0f ? d : 0.0f;
    mk[e] = d > 0.0f;
    any = any || mk[e];
  }
  if (!any) {  // fallback: one-hot argmax (first max, like np.argmax)
    int be = 0;
    float bv = lg[0];
#pragma unroll
    for (int e = 1; e < E_NUM; ++e) {
      if (lg[e] > bv) { bv = lg[e]; be = e; }
    }
#pragma unroll
    for (int e = 0; e < E_NUM; ++e) mk[e] = (e == be);
  }
  float mx = -1e30f;
#pragma unroll
  for (int e = 0; e < E_NUM; ++e) {
    float v = mk[e] ? gt[e] : -1e9f;
    if (v > mx) mx = v;
  }
  float sum = 0.0f;
  float ex[E_NUM];
#pragma unroll
  for (int e = 0; e < E_NUM; ++e) {
    ex[e] = mk[e] ? expf(gt[e] - mx) : 0.0f;
    sum += ex[e];
  }
  const float isum = 1.0f / sum;

  if (lane == 0) {
    float* lg_out = out + OUT_LOGITS + (size_t)t * E_NUM;
    float* mk_out = out + OUT_MASK + (size_t)t * E_NUM;
    float* rw = (float*)(wsb + WS_RW) + (size_t)t * E_NUM;
    unsigned mb = 0;
#pragma unroll
    for (int e = 0; e < E_NUM; ++e) {
      lg_out[e] = lg[e];
      mk_out[e] = mk[e] ? 1.0f : 0.0f;
      rw[e] = ex[e] * isum;
      if (mk[e]) mb |= (1u << e);
    }
    ((unsigned*)(wsb + WS_MASKB))[t] = mb;
  }
}

// Deterministic list build: one block per expert, prefix-scan over 8192 mask bits.
__global__ __launch_bounds__(1024) void build_lists_kernel(char* __restrict__ wsb) {
  const int e = blockIdx.x;
  const int tid = threadIdx.x;
  const unsigned* maskb = (const unsigned*)(wsb + WS_MASKB);
  const int t0 = tid * 8;
  unsigned flags = 0;
#pragma unroll
  for (int j = 0; j < 8; ++j)
    if (maskb[t0 + j] & (1u << e)) flags |= (1u << j);
  const int cnt = __popc(flags);
  const int lane = tid & 63, wid = tid >> 6;
  int v = cnt;
#pragma unroll
  for (int off = 1; off < 64; off <<= 1) {
    int u = __shfl_up(v, off);
    if (lane >= off) v += u;
  }
  __shared__ int wsum[16];
  if (lane == 63) wsum[wid] = v;
  __syncthreads();
  if (tid == 0) {
    int run = 0;
#pragma unroll
    for (int i = 0; i < 16; ++i) {
      int c = wsum[i];
      wsum[i] = run;
      run += c;
    }
    ((int*)(wsb + WS_COUNTS))[e] = run;
  }
  __syncthreads();
  int pos = wsum[wid] + v - cnt;  // exclusive prefix for this thread
  int* lists = (int*)(wsb + WS_LISTS) + e * T_TOK;
  int* posm = (int*)(wsb + WS_POS);
#pragma unroll
  for (int j = 0; j < 8; ++j) {
    const int t = t0 + j;
    int p = -1;
    if (flags & (1u << j)) {
      p = pos++;
      lists[p] = t;
    }
    posm[t * E_NUM + e] = p;
  }
}

// Tiled transpose+convert: src f32 [E][R][Cin] -> dst bf16 [E][Cin][R]
__global__ void transpose_kernel(const float* __restrict__ src, unsigned short* __restrict__ dst,
                                 int R, int Cin) {
  const int e = blockIdx.z;
  const int rt = blockIdx.y * 64, ct = blockIdx.x * 64;
  const float* se = src + (size_t)e * R * Cin;
  unsigned short* de = dst + (size_t)e * R * Cin;
  __shared__ unsigned short tile[64][68];
  const int tid = threadIdx.x;
  const int tr = tid >> 4, tc = (tid & 15) * 4;
#pragma unroll
  for (int it = 0; it < 4; ++it) {
    const int r = tr + it * 16;
    const float4 v = *(const float4*)(se + (size_t)(rt + r) * Cin + ct + tc);
    tile[tc + 0][r] = f2bf(v.x);
    tile[tc + 1][r] = f2bf(v.y);
    tile[tc + 2][r] = f2bf(v.z);
    tile[tc + 3][r] = f2bf(v.w);
  }
  __syncthreads();
#pragma unroll
  for (int it = 0; it < 4; ++it) {
    const int c = tr + it * 16;
    ushort4 o = *(const ushort4*)&tile[c][tc];
    *(ushort4*)(de + (size_t)(ct + c) * R + rt + tc) = o;
  }
}

// ---- Tiled grouped GEMM engine: 256 thr / 4 waves, tile M=64 N=128 BK=64 ----
// LDS: A[64][64] + B[128][64] bf16, XOR slot-swizzle (slot^(row&7)) on 16B slots.

// Stage 1: H[e][pos][i] = gelu(Xg @ W1T^t), bf16 out via LDS repack.
__global__ __launch_bounds__(256) void h_kernel(const char* __restrict__ wsb,
                                                const unsigned short* __restrict__ wt,
                                                unsigned short* __restrict__ hbuf) {
  const int e = blockIdx.x;
  const int ne = min(((const int*)(wsb + WS_COUNTS))[e], CAP);
  const int m0 = blockIdx.y * 64;
  if (m0 >= ne) return;
  const int i0 = blockIdx.z * 128;

  __shared__ unsigned short smem[12288];  // A: [0,4096) halves, B: [4096,12288)
  __shared__ int tl[64];
  const int tid = threadIdx.x;
  const int* lists = (const int*)(wsb + WS_LISTS);
  if (tid < 64) tl[tid] = lists[e * T_TOK + min(m0 + tid, ne - 1)];
  __syncthreads();

  const unsigned short* xb = (const unsigned short*)(wsb + WS_XB);
  const unsigned short* w1t = wt + (size_t)e * I_DIM * C_DIM;

  const unsigned short* srcA[2];
  int dstA[2];
#pragma unroll
  for (int it = 0; it < 2; ++it) {
    const int p = tid + it * 256, row = p >> 3, slot = p & 7;
    srcA[it] = xb + (size_t)tl[row] * C_DIM + slot * 8;
    dstA[it] = row * 64 + (slot ^ (row & 7)) * 8;
  }
  const unsigned short* srcB[4];
  int dstB[4];
#pragma unroll
  for (int it = 0; it < 4; ++it) {
    const int p = tid + it * 256, row = p >> 3, slot = p & 7;
    srcB[it] = w1t + (size_t)(i0 + row) * C_DIM + slot * 8;
    dstB[it] = 4096 + row * 64 + (slot ^ (row & 7)) * 8;
  }

  const int lane = tid & 63, wv = tid >> 6, wr = wv >> 1, wc = wv & 1;
  const int g = lane >> 4, l15 = lane & 15;
  const f32x4 zero4 = {0.f, 0.f, 0.f, 0.f};
  f32x4 acc[2][4];
#pragma unroll
  for (int m = 0; m < 2; ++m)
#pragma unroll
    for (int n = 0; n < 4; ++n) acc[m][n] = zero4;

  uint4 pa0 = *(const uint4*)srcA[0], pa1 = *(const uint4*)srcA[1];
  uint4 pb0 = *(const uint4*)srcB[0], pb1 = *(const uint4*)srcB[1];
  uint4 pb2 = *(const uint4*)srcB[2], pb3 = *(const uint4*)srcB[3];

#define NKH (C_DIM / 64)
  for (int ks = 0; ks < NKH; ++ks) {
    __syncthreads();  // previous compute's ds_reads done
    *(uint4*)(smem + dstA[0]) = pa0;
    *(uint4*)(smem + dstA[1]) = pa1;
    *(uint4*)(smem + dstB[0]) = pb0;
    *(uint4*)(smem + dstB[1]) = pb1;
    *(uint4*)(smem + dstB[2]) = pb2;
    *(uint4*)(smem + dstB[3]) = pb3;
    if (ks + 1 < NKH) {  // issue next-step loads; land under compute
      const int kn = (ks + 1) * 64;
      pa0 = *(const uint4*)(srcA[0] + kn);
      pa1 = *(const uint4*)(srcA[1] + kn);
      pb0 = *(const uint4*)(srcB[0] + kn);
      pb1 = *(const uint4*)(srcB[1] + kn);
      pb2 = *(const uint4*)(srcB[2] + kn);
      pb3 = *(const uint4*)(srcB[3] + kn);
    }
    __syncthreads();
#pragma unroll
    for (int sub = 0; sub < 2; ++sub) {
      const int sg = (sub << 2) | g;
      bf16x8 af[2], bf[4];
#pragma unroll
      for (int m = 0; m < 2; ++m) {
        const int r = wr * 32 + m * 16 + l15;
        af[m] = ldb8(smem + r * 64 + (sg ^ (r & 7)) * 8);
      }
#pragma unroll
      for (int n = 0; n < 4; ++n) {
        const int rb = wc * 64 + n * 16 + l15;
        bf[n] = ldb8(smem + 4096 + rb * 64 + (sg ^ (rb & 7)) * 8);
      }
#pragma unroll
      for (int m = 0; m < 2; ++m)
#pragma unroll
        for (int n = 0; n < 4; ++n)
          acc[m][n] = __builtin_amdgcn_mfma_f32_16x16x32_bf16(af[m], bf[n], acc[m][n], 0, 0, 0);
    }
  }

  // epilogue: gelu -> bf16 -> LDS pack [64][136] -> coalesced 16B stores
  __syncthreads();
#pragma unroll
  for (int m = 0; m < 2; ++m)
#pragma unroll
    for (int n = 0; n < 4; ++n) {
      const int row = wr * 32 + m * 16 + g * 4;
      const int col = wc * 64 + n * 16 + l15;
#pragma unroll
      for (int rr = 0; rr < 4; ++rr)
        smem[(row + rr) * 136 + col] = f2bf(gelu_f(acc[m][n][rr]));
    }
  __syncthreads();
  {
    const int row = tid >> 2;
    unsigned short* hd = hbuf + (size_t)(e * CAP + m0 + row) * I_DIM + i0;
#pragma unroll
    for (int s = 0; s < 4; ++s) {
      const int colh = ((tid & 3) * 4 + s) * 8;
      *(uint4*)(hd + colh) = *(const uint4*)(smem + row * 136 + colh);
    }
  }
}

// Stage 2: full[t][e][:] = H[e][pos][:] @ W2T^t (k = full I).
__global__ __launch_bounds__(256) void o_kernel(const char* __restrict__ wsb,
                                                const unsigned short* __restrict__ wt,
                                                const unsigned short* __restrict__ hbuf,
                                                float* __restrict__ out) {
  const int e = blockIdx.x;
  const int ne = min(((const int*)(wsb + WS_COUNTS))[e], CAP);
  const int m0 = blockIdx.y * 64;
  if (m0 >= ne) return;
  const int n0 = blockIdx.z * 128;

  __shared__ unsigned short smem[12288];
  __shared__ int tl[64];
  const int tid = threadIdx.x;
  const int* lists = (const int*)(wsb + WS_LISTS);
  if (tid < 64) tl[tid] = lists[e * T_TOK + min(m0 + tid, ne - 1)];

  const unsigned short* hb = hbuf + (size_t)e * CAP * I_DIM;
  const unsigned short* w2t = wt + (size_t)e * C_DIM * I_DIM;

  const unsigned short* srcA[2];
  int dstA[2];
#pragma unroll
  for (int it = 0; it < 2; ++it) {
    const int p = tid + it * 256, row = p >> 3, slot = p & 7;
    srcA[it] = hb + (size_t)(m0 + row) * I_DIM + slot * 8;
    dstA[it] = row * 64 + (slot ^ (row & 7)) * 8;
  }
  const unsigned short* srcB[4];
  int dstB[4];
#pragma unroll
  for (int it = 0; it < 4; ++it) {
    const int p = tid + it * 256, row = p >> 3, slot = p & 7;
    srcB[it] = w2t + (size_t)(n0 + row) * I_DIM + slot * 8;
    dstB[it] = 4096 + row * 64 + (slot ^ (row & 7)) * 8;
  }

  const int lane = tid & 63, wv = tid >> 6, wr = wv >> 1, wc = wv & 1;
  const int g = lane >> 4, l15 = lane & 15;
  const f32x4 zero4 = {0.f, 0.f, 0.f, 0.f};
  f32x4 acc[2][4];
#pragma unroll
  for (int m = 0; m < 2; ++m)
#pragma unroll
    for (int n = 0; n < 4; ++n) acc[m][n] = zero4;

  uint4 pa0 = *(const uint4*)srcA[0], pa1 = *(const uint4*)srcA[1];
  uint4 pb0 = *(const uint4*)srcB[0], pb1 = *(const uint4*)srcB[1];
  uint4 pb2 = *(const uint4*)srcB[2], pb3 = *(const uint4*)srcB[3];

#define NKO (I_DIM / 64)
  for (int ks = 0; ks < NKO; ++ks) {
    __syncthreads();
    *(uint4*)(smem + dstA[0]) = pa0;
    *(uint4*)(smem + dstA[1]) = pa1;
    *(uint4*)(smem + dstB[0]) = pb0;
    *(uint4*)(smem + dstB[1]) = pb1;
    *(uint4*)(smem + dstB[2]) = pb2;
    *(uint4*)(smem + dstB[3]) = pb3;
    if (ks + 1 < NKO) {
      const int kn = (ks + 1) * 64;
      pa0 = *(const uint4*)(srcA[0] + kn);
      pa1 = *(const uint4*)(srcA[1] + kn);
      pb0 = *(const uint4*)(srcB[0] + kn);
      pb1 = *(const uint4*)(srcB[1] + kn);
      pb2 = *(const uint4*)(srcB[2] + kn);
      pb3 = *(const uint4*)(srcB[3] + kn);
    }
    __syncthreads();
#pragma unroll
    for (int sub = 0; sub < 2; ++sub) {
      const int sg = (sub << 2) | g;
      bf16x8 af[2], bf[4];
#pragma unroll
      for (int m = 0; m < 2; ++m) {
        const int r = wr * 32 + m * 16 + l15;
        af[m] = ldb8(smem + r * 64 + (sg ^ (r & 7)) * 8);
      }
#pragma unroll
      for (int n = 0; n < 4; ++n) {
        const int rb = wc * 64 + n * 16 + l15;
        bf[n] = ldb8(smem + 4096 + rb * 64 + (sg ^ (rb & 7)) * 8);
      }
#pragma unroll
      for (int m = 0; m < 2; ++m)
#pragma unroll
        for (int n = 0; n < 4; ++n)
          acc[m][n] = __builtin_amdgcn_mfma_f32_16x16x32_bf16(af[m], bf[n], acc[m][n], 0, 0, 0);
    }
  }

  // epilogue: plain stores into full (block owns its rows x col-slice)
#pragma unroll
  for (int m = 0; m < 2; ++m) {
#pragma unroll
    for (int rr = 0; rr < 4; ++rr) {
      const int row = wr * 32 + m * 16 + g * 4 + rr;
      if (m0 + row < ne) {
        float* dst = out + OUT_FULL + ((size_t)tl[row] * E_NUM + e) * C_DIM + n0 + wc * 64 + l15;
#pragma unroll
        for (int n = 0; n < 4; ++n) dst[n * 16] = acc[m][n][rr];
      }
    }
  }
}

// Zero-fill inactive rows of full + final = sum_e rw * full (active rows already written).
__global__ void scatter_kernel(const char* __restrict__ wsb, float* __restrict__ out) {
  const int t = blockIdx.x;
  const int tid = threadIdx.x;  // 256
  __shared__ float rws[E_NUM];
  __shared__ int ps[E_NUM];
  if (tid < E_NUM) {
    rws[tid] = ((const float*)(wsb + WS_RW))[t * E_NUM + tid];
    ps[tid] = ((const int*)(wsb + WS_POS))[t * E_NUM + tid];
  }
  __syncthreads();
  float a0 = 0.f, a1 = 0.f;
  float* full = out + OUT_FULL + (size_t)t * E_NUM * C_DIM;
#pragma unroll 1
  for (int e = 0; e < E_NUM; ++e) {
    const int p = ps[e];
    if (p >= 0 && p < CAP) {
      const float w = rws[e];
      a0 += w * full[e * C_DIM + tid];
      a1 += w * full[e * C_DIM + tid + 256];
    } else {
      full[e * C_DIM + tid] = 0.f;
      full[e * C_DIM + tid + 256] = 0.f;
    }
  }
  out[(size_t)t * C_DIM + tid] = a0;
  out[(size_t)t * C_DIM + tid + 256] = a1;
}

extern "C" void kernel_launch(void* const* d_in, const int* in_sizes, int n_in,
                              void* d_out, int out_size, void* d_ws, size_t ws_size,
                              hipStream_t stream) {
  const float* x = (const float*)d_in[0];
  const float* sim = (const float*)d_in[1];
  const float* gates = (const float*)d_in[2];
  const float* w1 = (const float*)d_in[3];
  const float* w2 = (const float*)d_in[4];
  float* out = (float*)d_out;
  char* wsb = (char*)d_ws;
  unsigned short* wt = (unsigned short*)(wsb + WS_WT);
  unsigned short* hbuf = (unsigned short*)(wsb + WS_H);

  hipLaunchKernelGGL(prep_kernel, dim3(1), dim3(64), 0, stream, sim, gates, wsb);
  hipLaunchKernelGGL(router_kernel, dim3(T_TOK / 4), dim3(256), 0, stream, x, sim, wsb, out);
  hipLaunchKernelGGL(build_lists_kernel, dim3(E_NUM), dim3(1024), 0, stream, wsb);

  // W1 [E][512][2048] -> WT = W1T [E][2048][512]
  hipLaunchKernelGGL(transpose_kernel, dim3(I_DIM / 64, C_DIM / 64, E_NUM), dim3(256), 0, stream,
                     w1, wt, C_DIM, I_DIM);
  hipLaunchKernelGGL(h_kernel, dim3(E_NUM, CAP / 64, I_DIM / 128), dim3(256), 0, stream,
                     wsb, wt, hbuf);
  // W2 [E][2048][512] -> WT = W2T [E][512][2048]  (reuses the same region)
  hipLaunchKernelGGL(transpose_kernel, dim3(C_DIM / 64, I_DIM / 64, E_NUM), dim3(256), 0, stream,
                     w2, wt, I_DIM, C_DIM);
  hipLaunchKernelGGL(o_kernel, dim3(E_NUM, CAP / 64, C_DIM / 128), dim3(256), 0, stream,
                     wsb, wt, hbuf, out);
  hipLaunchKernelGGL(scatter_kernel, dim3(T_TOK), dim3(256), 0, stream, wsb, out);
}

// Round 6
// 241.447 us; speedup vs baseline: 1.9364x; 1.0075x over previous
//
#include <hip/hip_runtime.h>
#include <hip/hip_bf16.h>
#include <math.h>

#define T_TOK 8192
#define C_DIM 512
#define I_DIM 2048
#define E_NUM 16
#define CAP 640

// ws layout (bytes); peak use ~86 MB (< proven 111 MB)
#define WS_COUNTS 0
#define WS_THR 64
#define WS_INVS 128
#define WS_RW 192
#define WS_LISTS 524480
#define WS_XB 1048768
#define WS_POS 9437376
#define WS_MASKB 9961664
#define WS_WT 10485760ull /* W2T bf16, 33.5 MB */
#define WS_H 44040192ull  /* bf16 H [E][CAP][I], 41.9 MB */

// out offsets (float elements)
#define OUT_FULL 4194304ull
#define OUT_LOGITS 71303168ull
#define OUT_MASK 71434240ull

typedef __attribute__((ext_vector_type(8))) short bf16x8;
typedef __attribute__((ext_vector_type(4))) float f32x4;

__device__ inline unsigned short f2bf(float f) {
  unsigned u = __float_as_uint(f);
  unsigned r = u + 0x7fffu + ((u >> 16) & 1u);
  return (unsigned short)(r >> 16);
}

__device__ inline bf16x8 ldb8(const unsigned short* p) {
  union { uint4 u; bf16x8 v; } w;
  w.u = *(const uint4*)p;
  return w.v;
}

__device__ inline float gelu_f(float x) {
  return 0.5f * x * (1.0f + erff(x * 0.7071067811865476f));
}

__global__ void prep_kernel(const float* __restrict__ sim, const float* __restrict__ gates,
                            char* __restrict__ wsb) {
  int e = threadIdx.x;
  if (e < E_NUM) {
    ((float*)(wsb + WS_THR))[e] = 1.0f / (1.0f + expf(-gates[e]));
    float ss = 0.0f;
    for (int c = 0; c < C_DIM; ++c) {
      float v = sim[c * E_NUM + e];
      ss += v * v;
    }
    float n = fmaxf(sqrtf(ss), 1e-12f);
    ((float*)(wsb + WS_INVS))[e] = 1.0f / n;
  }
}

// Per-token routing; sim staged to LDS with bank-exact swizzle idx=c*17+e+(c>>3).
__global__ __launch_bounds__(256) void router_kernel(const float* __restrict__ x,
                                                     const float* __restrict__ sim,
                                                     char* __restrict__ wsb,
                                                     float* __restrict__ out) {
  __shared__ float slds[8768];
  const int tid = threadIdx.x;
  for (int q = tid; q < C_DIM * E_NUM; q += 256)
    slds[(q >> 4) * 17 + (q & 15) + (q >> 7)] = sim[q];

  const int lane = tid & 63;
  const int t = blockIdx.x * 4 + (tid >> 6);

  const float4* xr = (const float4*)(x + (size_t)t * C_DIM + lane * 8);
  float4 v0 = xr[0], v1 = xr[1];
  float xv[8] = {v0.x, v0.y, v0.z, v0.w, v1.x, v1.y, v1.z, v1.w};

  unsigned p[4];
#pragma unroll
  for (int j = 0; j < 4; ++j)
    p[j] = (unsigned)f2bf(xv[2 * j]) | ((unsigned)f2bf(xv[2 * j + 1]) << 16);
  uint4 pk = {p[0], p[1], p[2], p[3]};
  *(uint4*)((unsigned short*)(wsb + WS_XB) + (size_t)t * C_DIM + lane * 8) = pk;

  __syncthreads();

  float ss = 0.0f;
  float acc[E_NUM];
#pragma unroll
  for (int e = 0; e < E_NUM; ++e) acc[e] = 0.0f;

  const int biL = lane * 137;  // idx(c=8*lane+j, e) = 137*lane + 17*j + e
#pragma unroll
  for (int j = 0; j < 8; ++j) {
    const float xd = xv[j];
    ss += xd * xd;
    const float* sp = slds + biL + 17 * j;
#pragma unroll
    for (int e = 0; e < E_NUM; ++e) acc[e] += xd * sp[e];
  }

#define BRED(v)                 \
  v += __shfl_xor(v, 32);       \
  v += __shfl_xor(v, 16);       \
  v += __shfl_xor(v, 8);        \
  v += __shfl_xor(v, 4);        \
  v += __shfl_xor(v, 2);        \
  v += __shfl_xor(v, 1);

  BRED(ss)
#pragma unroll
  for (int e = 0; e < E_NUM; ++e) { BRED(acc[e]) }

  const float invx = 1.0f / fmaxf(sqrtf(ss), 1e-12f);
  const float* thr = (const float*)(wsb + WS_THR);
  const float* invs = (const float*)(wsb + WS_INVS);

  float lg[E_NUM], gt[E_NUM];
  bool mk[E_NUM];
  bool any = false;
#pragma unroll
  for (int e = 0; e < E_NUM; ++e) {
    lg[e] = acc[e] * invx * invs[e];
    float d = lg[e] - thr[e];
    gt[e] = d > 0.0f ? d : 0.0f;
    mk[e] = d > 0.0f;
    any = any || mk[e];
  }
  if (!any) {  // fallback: one-hot argmax (first max, like np.argmax)
    int be = 0;
    float bv = lg[0];
#pragma unroll
    for (int e = 1; e < E_NUM; ++e) {
      if (lg[e] > bv) { bv = lg[e]; be = e; }
    }
#pragma unroll
    for (int e = 0; e < E_NUM; ++e) mk[e] = (e == be);
  }
  float mx = -1e30f;
#pragma unroll
  for (int e = 0; e < E_NUM; ++e) {
    float v = mk[e] ? gt[e] : -1e9f;
    if (v > mx) mx = v;
  }
  float sum = 0.0f;
  float ex[E_NUM];
#pragma unroll
  for (int e = 0; e < E_NUM; ++e) {
    ex[e] = mk[e] ? expf(gt[e] - mx) : 0.0f;
    sum += ex[e];
  }
  const float isum = 1.0f / sum;

  if (lane == 0) {
    float* lg_out = out + OUT_LOGITS + (size_t)t * E_NUM;
    float* mk_out = out + OUT_MASK + (size_t)t * E_NUM;
    float* rw = (float*)(wsb + WS_RW) + (size_t)t * E_NUM;
    unsigned mb = 0;
#pragma unroll
    for (int e = 0; e < E_NUM; ++e) {
      lg_out[e] = lg[e];
      mk_out[e] = mk[e] ? 1.0f : 0.0f;
      rw[e] = ex[e] * isum;
      if (mk[e]) mb |= (1u << e);
    }
    ((unsigned*)(wsb + WS_MASKB))[t] = mb;
  }
}

// Deterministic list build: one block per expert, prefix-scan over 8192 mask bits.
__global__ __launch_bounds__(1024) void build_lists_kernel(char* __restrict__ wsb) {
  const int e = blockIdx.x;
  const int tid = threadIdx.x;
  const unsigned* maskb = (const unsigned*)(wsb + WS_MASKB);
  const int t0 = tid * 8;
  unsigned flags = 0;
#pragma unroll
  for (int j = 0; j < 8; ++j)
    if (maskb[t0 + j] & (1u << e)) flags |= (1u << j);
  const int cnt = __popc(flags);
  const int lane = tid & 63, wid = tid >> 6;
  int v = cnt;
#pragma unroll
  for (int off = 1; off < 64; off <<= 1) {
    int u = __shfl_up(v, off);
    if (lane >= off) v += u;
  }
  __shared__ int wsum[16];
  if (lane == 63) wsum[wid] = v;
  __syncthreads();
  if (tid == 0) {
    int run = 0;
#pragma unroll
    for (int i = 0; i < 16; ++i) {
      int c = wsum[i];
      wsum[i] = run;
      run += c;
    }
    ((int*)(wsb + WS_COUNTS))[e] = run;
  }
  __syncthreads();
  int pos = wsum[wid] + v - cnt;  // exclusive prefix for this thread
  int* lists = (int*)(wsb + WS_LISTS) + e * T_TOK;
  int* posm = (int*)(wsb + WS_POS);
#pragma unroll
  for (int j = 0; j < 8; ++j) {
    const int t = t0 + j;
    int p = -1;
    if (flags & (1u << j)) {
      p = pos++;
      lists[p] = t;
    }
    posm[t * E_NUM + e] = p;
  }
}

// Tiled transpose+convert: src f32 [E][R][Cin] -> dst bf16 [E][Cin][R]  (W2 only now)
__global__ void transpose_kernel(const float* __restrict__ src, unsigned short* __restrict__ dst,
                                 int R, int Cin) {
  const int e = blockIdx.z;
  const int rt = blockIdx.y * 64, ct = blockIdx.x * 64;
  const float* se = src + (size_t)e * R * Cin;
  unsigned short* de = dst + (size_t)e * R * Cin;
  __shared__ unsigned short tile[64][68];
  const int tid = threadIdx.x;
  const int tr = tid >> 4, tc = (tid & 15) * 4;
#pragma unroll
  for (int it = 0; it < 4; ++it) {
    const int r = tr + it * 16;
    const float4 v = *(const float4*)(se + (size_t)(rt + r) * Cin + ct + tc);
    tile[tc + 0][r] = f2bf(v.x);
    tile[tc + 1][r] = f2bf(v.y);
    tile[tc + 2][r] = f2bf(v.z);
    tile[tc + 3][r] = f2bf(v.w);
  }
  __syncthreads();
#pragma unroll
  for (int it = 0; it < 4; ++it) {
    const int c = tr + it * 16;
    ushort4 o = *(const ushort4*)&tile[c][tc];
    *(ushort4*)(de + (size_t)(ct + c) * R + rt + tc) = o;
  }
}

// Stage 1 (weight-resident, fused W1 transpose): block=(e, itile of 128).
// Prologue: W1 slice [512 k][128 i] f32 -> bf16 LDS [i][k] swizzled (once).
// m-loop: stage X chunks, MFMA, gelu, pack H bf16 -> global.
__device__ inline int w1swz(int i, int kslot) {
  const int mi = (i & 7) ^ (((i >> 3) & 3) << 1);
  return i * 512 + ((kslot ^ mi) << 3);
}

__global__ __launch_bounds__(512) void h_kernel(const float* __restrict__ w1,
                                                const char* __restrict__ wsb,
                                                unsigned short* __restrict__ hbuf) {
  const int e = blockIdx.x;
  const int i0 = blockIdx.y * 128;
  const int ne = min(((const int*)(wsb + WS_COUNTS))[e], CAP);
  if (ne == 0) return;

  __shared__ unsigned short sW[128 * 512];  // 128 KB
  __shared__ unsigned short sX[64 * 128];   // 16 KB (X chunk / H pack)
  __shared__ int tl[64];

  const int tid = threadIdx.x;
  const int* lists = (const int*)(wsb + WS_LISTS);
  const unsigned short* xb = (const unsigned short*)(wsb + WS_XB);

  // prologue: stage+transpose W1
  const float* w1p = w1 + (size_t)e * C_DIM * I_DIM + i0;
#pragma unroll 4
  for (int it2 = 0; it2 < 32; ++it2) {
    const int q = tid + it2 * 512;
    const int k = q >> 5, i4 = q & 31;
    const float4 v = *(const float4*)(w1p + (size_t)k * I_DIM + i4 * 4);
    const int ks = k >> 3, kr = k & 7;
    sW[w1swz(i4 * 4 + 0, ks) + kr] = f2bf(v.x);
    sW[w1swz(i4 * 4 + 1, ks) + kr] = f2bf(v.y);
    sW[w1swz(i4 * 4 + 2, ks) + kr] = f2bf(v.z);
    sW[w1swz(i4 * 4 + 3, ks) + kr] = f2bf(v.w);
  }
  __syncthreads();

  const int lane = tid & 63, wv = tid >> 6;
  const int wa = wv >> 2, wb = wv & 3;
  const int g = lane >> 4, l15 = lane & 15;
  const f32x4 zero4 = {0.f, 0.f, 0.f, 0.f};

  for (int mt = 0; mt * 64 < ne; ++mt) {
    const int m0 = mt * 64;
    if (tid < 64) tl[tid] = lists[e * T_TOK + min(m0 + tid, ne - 1)];
    __syncthreads();

    f32x4 acc[2][2];
#pragma unroll
    for (int mf = 0; mf < 2; ++mf)
#pragma unroll
      for (int nf = 0; nf < 2; ++nf) acc[mf][nf] = zero4;

    for (int kg = 0; kg < 4; ++kg) {
      if (kg) __syncthreads();
#pragma unroll
      for (int st = 0; st < 2; ++st) {
        const int q = tid + st * 512, m = q >> 4, slot = q & 15;
        *(uint4*)(sX + m * 128 + ((slot ^ (m & 7)) << 3)) =
            *(const uint4*)(xb + (size_t)tl[m] * C_DIM + kg * 128 + slot * 8);
      }
      __syncthreads();
#pragma unroll
      for (int s = 0; s < 4; ++s) {
        bf16x8 af[2], bfr[2];
#pragma unroll
        for (int mf = 0; mf < 2; ++mf) {
          const int m = wa * 32 + mf * 16 + l15;
          af[mf] = ldb8(sX + m * 128 + (((s * 4 + g) ^ (m & 7)) << 3));
        }
        const int kslot = kg * 16 + s * 4 + g;
#pragma unroll
        for (int nf = 0; nf < 2; ++nf) {
          const int i = wb * 32 + nf * 16 + l15;
          bfr[nf] = ldb8(sW + w1swz(i, kslot));
        }
#pragma unroll
        for (int mf = 0; mf < 2; ++mf)
#pragma unroll
          for (int nf = 0; nf < 2; ++nf)
            acc[mf][nf] = __builtin_amdgcn_mfma_f32_16x16x32_bf16(af[mf], bfr[nf], acc[mf][nf], 0, 0, 0);
      }
    }

    // epilogue: gelu -> bf16 pack in sX -> coalesced global stores
    __syncthreads();
#pragma unroll
    for (int mf = 0; mf < 2; ++mf)
#pragma unroll
      for (int nf = 0; nf < 2; ++nf) {
        const int col = wb * 32 + nf * 16 + l15;
#pragma unroll
        for (int rr = 0; rr < 4; ++rr) {
          const int row = wa * 32 + mf * 16 + g * 4 + rr;
          sX[row * 128 + col] = f2bf(gelu_f(acc[mf][nf][rr]));
        }
      }
    __syncthreads();
#pragma unroll
    for (int st = 0; st < 2; ++st) {
      const int q = tid + st * 512, row = q >> 4, slot = q & 15;
      *(uint4*)(hbuf + (size_t)(e * CAP + m0 + row) * I_DIM + i0 + slot * 8) =
          *(const uint4*)(sX + row * 128 + slot * 8);
    }
    __syncthreads();  // sX reads done before next mt's staging writes
  }
}

// Stage 2: full[t][e][:] = H[e][pos][:] @ W2T^t (k = full I). Unchanged from R5.
__global__ __launch_bounds__(256) void o_kernel(const char* __restrict__ wsb,
                                                const unsigned short* __restrict__ wt,
                                                const unsigned short* __restrict__ hbuf,
                                                float* __restrict__ out) {
  const int e = blockIdx.x;
  const int ne = min(((const int*)(wsb + WS_COUNTS))[e], CAP);
  const int m0 = blockIdx.y * 64;
  if (m0 >= ne) return;
  const int n0 = blockIdx.z * 128;

  __shared__ unsigned short smem[12288];
  __shared__ int tl[64];
  const int tid = threadIdx.x;
  const int* lists = (const int*)(wsb + WS_LISTS);
  if (tid < 64) tl[tid] = lists[e * T_TOK + min(m0 + tid, ne - 1)];

  const unsigned short* hb = hbuf + (size_t)e * CAP * I_DIM;
  const unsigned short* w2t = wt + (size_t)e * C_DIM * I_DIM;

  const unsigned short* srcA[2];
  int dstA[2];
#pragma unroll
  for (int it = 0; it < 2; ++it) {
    const int p = tid + it * 256, row = p >> 3, slot = p & 7;
    srcA[it] = hb + (size_t)(m0 + row) * I_DIM + slot * 8;
    dstA[it] = row * 64 + (slot ^ (row & 7)) * 8;
  }
  const unsigned short* srcB[4];
  int dstB[4];
#pragma unroll
  for (int it = 0; it < 4; ++it) {
    const int p = tid + it * 256, row = p >> 3, slot = p & 7;
    srcB[it] = w2t + (size_t)(n0 + row) * I_DIM + slot * 8;
    dstB[it] = 4096 + row * 64 + (slot ^ (row & 7)) * 8;
  }

  const int lane = tid & 63, wv = tid >> 6, wr = wv >> 1, wc = wv & 1;
  const int g = lane >> 4, l15 = lane & 15;
  const f32x4 zero4 = {0.f, 0.f, 0.f, 0.f};
  f32x4 acc[2][4];
#pragma unroll
  for (int m = 0; m < 2; ++m)
#pragma unroll
    for (int n = 0; n < 4; ++n) acc[m][n] = zero4;

  uint4 pa0 = *(const uint4*)srcA[0], pa1 = *(const uint4*)srcA[1];
  uint4 pb0 = *(const uint4*)srcB[0], pb1 = *(const uint4*)srcB[1];
  uint4 pb2 = *(const uint4*)srcB[2], pb3 = *(const uint4*)srcB[3];

#define NKO (I_DIM / 64)
  for (int ks = 0; ks < NKO; ++ks) {
    __syncthreads();
    *(uint4*)(smem + dstA[0]) = pa0;
    *(uint4*)(smem + dstA[1]) = pa1;
    *(uint4*)(smem + dstB[0]) = pb0;
    *(uint4*)(smem + dstB[1]) = pb1;
    *(uint4*)(smem + dstB[2]) = pb2;
    *(uint4*)(smem + dstB[3]) = pb3;
    if (ks + 1 < NKO) {
      const int kn = (ks + 1) * 64;
      pa0 = *(const uint4*)(srcA[0] + kn);
      pa1 = *(const uint4*)(srcA[1] + kn);
      pb0 = *(const uint4*)(srcB[0] + kn);
      pb1 = *(const uint4*)(srcB[1] + kn);
      pb2 = *(const uint4*)(srcB[2] + kn);
      pb3 = *(const uint4*)(srcB[3] + kn);
    }
    __syncthreads();
#pragma unroll
    for (int sub = 0; sub < 2; ++sub) {
      const int sg = (sub << 2) | g;
      bf16x8 af[2], bf[4];
#pragma unroll
      for (int m = 0; m < 2; ++m) {
        const int r = wr * 32 + m * 16 + l15;
        af[m] = ldb8(smem + r * 64 + (sg ^ (r & 7)) * 8);
      }
#pragma unroll
      for (int n = 0; n < 4; ++n) {
        const int rb = wc * 64 + n * 16 + l15;
        bf[n] = ldb8(smem + 4096 + rb * 64 + (sg ^ (rb & 7)) * 8);
      }
#pragma unroll
      for (int m = 0; m < 2; ++m)
#pragma unroll
        for (int n = 0; n < 4; ++n)
          acc[m][n] = __builtin_amdgcn_mfma_f32_16x16x32_bf16(af[m], bf[n], acc[m][n], 0, 0, 0);
    }
  }

#pragma unroll
  for (int m = 0; m < 2; ++m) {
#pragma unroll
    for (int rr = 0; rr < 4; ++rr) {
      const int row = wr * 32 + m * 16 + g * 4 + rr;
      if (m0 + row < ne) {
        float* dst = out + OUT_FULL + ((size_t)tl[row] * E_NUM + e) * C_DIM + n0 + wc * 64 + l15;
#pragma unroll
        for (int n = 0; n < 4; ++n) dst[n * 16] = acc[m][n][rr];
      }
    }
  }
}

// Zero-fill inactive rows of full + final = sum_e rw*full, float4 throughout. 2 tokens/block.
__global__ __launch_bounds__(256) void scatter_kernel(const char* __restrict__ wsb,
                                                      float* __restrict__ out) {
  const int tid = threadIdx.x;
  const int t = blockIdx.x * 2 + (tid >> 7);
  const int q = tid & 127;
  __shared__ float rws[2][E_NUM];
  __shared__ int ps[2][E_NUM];
  if (tid < 32) {
    const int tt = blockIdx.x * 2 + (tid >> 4);
    rws[tid >> 4][tid & 15] = ((const float*)(wsb + WS_RW))[tt * E_NUM + (tid & 15)];
    ps[tid >> 4][tid & 15] = ((const int*)(wsb + WS_POS))[tt * E_NUM + (tid & 15)];
  }
  __syncthreads();
  const int hw = tid >> 7;
  float4 a = {0.f, 0.f, 0.f, 0.f};
  float4* full4 = (float4*)(out + OUT_FULL) + (size_t)t * E_NUM * 128;
  const float4 z4 = {0.f, 0.f, 0.f, 0.f};
#pragma unroll 1
  for (int e = 0; e < E_NUM; ++e) {
    const int p = ps[hw][e];
    if (p >= 0 && p < CAP) {
      const float w = rws[hw][e];
      float4 v = full4[e * 128 + q];
      a.x += w * v.x; a.y += w * v.y; a.z += w * v.z; a.w += w * v.w;
    } else {
      full4[e * 128 + q] = z4;
    }
  }
  ((float4*)out)[(size_t)t * 128 + q] = a;
}

extern "C" void kernel_launch(void* const* d_in, const int* in_sizes, int n_in,
                              void* d_out, int out_size, void* d_ws, size_t ws_size,
                              hipStream_t stream) {
  const float* x = (const float*)d_in[0];
  const float* sim = (const float*)d_in[1];
  const float* gates = (const float*)d_in[2];
  const float* w1 = (const float*)d_in[3];
  const float* w2 = (const float*)d_in[4];
  float* out = (float*)d_out;
  char* wsb = (char*)d_ws;
  unsigned short* wt = (unsigned short*)(wsb + WS_WT);
  unsigned short* hbuf = (unsigned short*)(wsb + WS_H);

  hipLaunchKernelGGL(prep_kernel, dim3(1), dim3(64), 0, stream, sim, gates, wsb);
  hipLaunchKernelGGL(router_kernel, dim3(T_TOK / 4), dim3(256), 0, stream, x, sim, wsb, out);
  hipLaunchKernelGGL(build_lists_kernel, dim3(E_NUM), dim3(1024), 0, stream, wsb);
  // W2 [E][2048][512] -> W2T [E][512][2048]
  hipLaunchKernelGGL(transpose_kernel, dim3(C_DIM / 64, I_DIM / 64, E_NUM), dim3(256), 0, stream,
                     w2, wt, I_DIM, C_DIM);
  hipLaunchKernelGGL(h_kernel, dim3(E_NUM, I_DIM / 128), dim3(512), 0, stream, w1, wsb, hbuf);
  hipLaunchKernelGGL(o_kernel, dim3(E_NUM, CAP / 64, C_DIM / 128), dim3(256), 0, stream,
                     wsb, wt, hbuf, out);
  hipLaunchKernelGGL(scatter_kernel, dim3(T_TOK / 2), dim3(256), 0, stream, wsb, out);
}